// Round 3
// baseline (18217.473 us; speedup 1.0000x reference)
//
#include <hip/hip_runtime.h>

typedef unsigned short u16;
typedef __attribute__((ext_vector_type(8))) short bf16x8;
typedef __attribute__((ext_vector_type(4))) float f32x4;

#define BSZ 32
#define TT 512
#define GG (BSZ*TT)      // 16384
#define NNODE 64
#define EE 126
#define H8 1024
#define H3 3072

__device__ __forceinline__ float b2f(u16 u){
  union { unsigned i; float f; } v; v.i = ((unsigned)u) << 16; return v.f;
}
__device__ __forceinline__ u16 f2b(float f){
  unsigned i = __float_as_uint(f);
  unsigned r = (i + 0x7FFFu + ((i >> 16) & 1u)) >> 16;   // RNE
  return (u16)r;
}
__device__ __forceinline__ float sigm(float x){ return 1.f/(1.f+__expf(-x)); }
__device__ __forceinline__ float tanh_f(float x){
  float xc = fminf(fmaxf(x, -15.f), 15.f);
  float e = __expf(2.f*xc);
  return (e-1.f)/(e+1.f);
}

// ---------------- dtype detection: *flag = 1 if inputs are fp32 ----------------
// Even-indexed u16s of true-bf16 N(0,1) data have exponents in ~[117,129];
// low halves of fp32 words are uniform-random bits -> ~86% outside [100,134].
__global__ __launch_bounds__(256) void detect_dtype(const void* xraw, int* flag){
  __shared__ int cnt;
  if (threadIdx.x == 0) cnt = 0;
  __syncthreads();
  const u16* p = (const u16*)xraw;
  u16 u = p[2*threadIdx.x];
  int e = (u >> 7) & 0xFF;
  int weird = (e < 100 || e > 134) ? 1 : 0;
  atomicAdd(&cnt, weird);
  __syncthreads();
  if (threadIdx.x == 0) *flag = (cnt > 128) ? 1 : 0;
}

// canonicalize a float tensor to bf16 (pass-through copy if already bf16)
__global__ __launch_bounds__(256) void cvt_bf16(const void* __restrict__ in,
                                                u16* __restrict__ out, int n,
                                                const int* __restrict__ flag){
  int i = blockIdx.x*256 + threadIdx.x;
  if (i >= n) return;
  if (*flag) out[i] = f2b(((const float*)in)[i]);
  else       out[i] = ((const u16*)in)[i];
}

// ---------------- GCN: one block per graph, one thread per node ----------------
__global__ __launch_bounds__(64) void gcn_kernel(
    const u16* __restrict__ x, const int* __restrict__ ei,
    const u16* __restrict__ w1, const u16* __restrict__ b1,
    const u16* __restrict__ w2, const u16* __restrict__ b2,
    const u16* __restrict__ cw, const u16* __restrict__ cb,
    u16* __restrict__ res)
{
  __shared__ int se[EE], de[EE];
  __shared__ float dinv[NNODE];
  __shared__ float nrm[EE];
  __shared__ float hs[NNODE][4];
  const int n = threadIdx.x;
  const int g = blockIdx.x;
  for (int e = n; e < EE; e += 64){ se[e] = ei[e]; de[e] = ei[EE + e]; }
  __syncthreads();
  int cnt = 0;
  for (int e = 0; e < EE; e++) cnt += (de[e] == n) ? 1 : 0;
  float di = rsqrtf(1.0f + (float)cnt);   // deg includes self-loop
  dinv[n] = di;
  float x0 = b2f(x[((size_t)g*NNODE + n)*2 + 0]);
  float x1 = b2f(x[((size_t)g*NNODE + n)*2 + 1]);
  float hw[4];
  #pragma unroll
  for (int c = 0; c < 4; c++) hw[c] = x0*b2f(w1[c]) + x1*b2f(w1[4+c]);
  #pragma unroll
  for (int c = 0; c < 4; c++) hs[n][c] = hw[c];
  __syncthreads();
  for (int e = n; e < EE; e += 64) nrm[e] = dinv[se[e]] * dinv[de[e]];
  __syncthreads();
  float selfc = di*di;
  float agg[4];
  #pragma unroll
  for (int c = 0; c < 4; c++) agg[c] = hw[c]*selfc;
  for (int e = 0; e < EE; e++){
    if (de[e] == n){
      float w = nrm[e]; int s = se[e];
      #pragma unroll
      for (int c = 0; c < 4; c++) agg[c] += hs[s][c]*w;
    }
  }
  float h1[4];
  #pragma unroll
  for (int c = 0; c < 4; c++) h1[c] = tanh_f(agg[c] + b2f(b1[c]));
  __syncthreads();              // everyone done reading hs (conv1)
  float hw2[2];
  #pragma unroll
  for (int c = 0; c < 2; c++){
    float s = 0.f;
    #pragma unroll
    for (int k = 0; k < 4; k++) s += h1[k]*b2f(w2[k*2+c]);
    hw2[c] = s;
    hs[n][c] = s;
  }
  __syncthreads();
  float agg2[2] = { hw2[0]*selfc, hw2[1]*selfc };
  for (int e = 0; e < EE; e++){
    if (de[e] == n){
      float w = nrm[e]; int s = se[e];
      agg2[0] += hs[s][0]*w;
      agg2[1] += hs[s][1]*w;
    }
  }
  float h2a = tanh_f(agg2[0] + b2f(b2[0]));
  float h2b = tanh_f(agg2[1] + b2f(b2[1]));
  #pragma unroll
  for (int c = 0; c < 2; c++){
    float o = h2a*b2f(cw[c]) + h2b*b2f(cw[2+c]) + b2f(cb[c]);
    res[(size_t)g*128 + n*2 + c] = f2b(o);
  }
}

// ---------------- bf16 transpose: out[c][r] = in[r][c] ----------------
__global__ __launch_bounds__(256) void transpose_bf16(
    const u16* __restrict__ in, u16* __restrict__ out, int R, int C)
{
  __shared__ u16 tile[32][33];
  int c0 = blockIdx.x*32, r0 = blockIdx.y*32;
  for (int i = threadIdx.y; i < 32; i += 8)
    tile[i][threadIdx.x] = in[(size_t)(r0+i)*C + c0 + threadIdx.x];
  __syncthreads();
  for (int i = threadIdx.y; i < 32; i += 8)
    out[(size_t)(c0+i)*R + r0 + threadIdx.x] = tile[threadIdx.x][i];
}

// ---------------- C[M,N] = act(A[M,K] * Bm[N,K]^T + bias) ----------------
// WG tile 128x128, 4 waves in 2x2, each wave 64x64, MFMA 16x16x32 bf16.
// outflag: nullptr -> bf16 store; else *outflag==1 -> f32 store to C.
__global__ __launch_bounds__(256) void gemm_nt(
    const u16* __restrict__ A, const u16* __restrict__ Bm,
    const u16* __restrict__ bias, void* __restrict__ C,
    int M, int N, int K, int relu, const int* __restrict__ outflag)
{
  const int wave = threadIdx.x >> 6;
  const int lane = threadIdx.x & 63;
  const int wm = wave >> 1, wn = wave & 1;
  const int q = lane >> 4, lr = lane & 15;
  const int mBase = blockIdx.y*128 + wm*64;
  const int nBase = blockIdx.x*128 + wn*64;
  f32x4 acc[4][4] = {};
  const u16* ap[4]; const u16* bp[4];
  #pragma unroll
  for (int i = 0; i < 4; i++){
    ap[i] = A + (size_t)(mBase + i*16 + lr)*K + q*8;
    bp[i] = Bm + (size_t)(nBase + i*16 + lr)*K + q*8;
  }
  for (int kb = 0; kb < K; kb += 32){
    bf16x8 av[4], bv[4];
    #pragma unroll
    for (int i = 0; i < 4; i++){
      av[i] = *(const bf16x8*)ap[i]; bv[i] = *(const bf16x8*)bp[i];
      ap[i] += 32; bp[i] += 32;
    }
    #pragma unroll
    for (int mi = 0; mi < 4; mi++)
      #pragma unroll
      for (int ni = 0; ni < 4; ni++)
        acc[mi][ni] = __builtin_amdgcn_mfma_f32_16x16x32_bf16(av[mi], bv[ni], acc[mi][ni], 0, 0, 0);
  }
  const int of32 = outflag ? *outflag : 0;
  #pragma unroll
  for (int ni = 0; ni < 4; ni++){
    int col = nBase + ni*16 + lr;
    float bb = bias ? b2f(bias[col]) : 0.f;
    #pragma unroll
    for (int mi = 0; mi < 4; mi++){
      #pragma unroll
      for (int r = 0; r < 4; r++){
        int row = mBase + mi*16 + q*4 + r;
        float v = acc[mi][ni][r] + bb;
        if (relu) v = fmaxf(v, 0.f);
        size_t idx = (size_t)row*N + col;
        if (of32) ((float*)C)[idx] = v;
        else      ((u16*)C)[idx]   = f2b(v);
      }
    }
  }
}

// ---------------- device-scope grid barrier (64 co-resident WGs) ----------------
__device__ __forceinline__ void grid_barrier(int* cnt, int* gen, int nwg)
{
  __syncthreads();
  if (threadIdx.x == 0){
    __threadfence();   // release
    int g = __hip_atomic_load(gen, __ATOMIC_RELAXED, __HIP_MEMORY_SCOPE_AGENT);
    int a = __hip_atomic_fetch_add(cnt, 1, __ATOMIC_ACQ_REL, __HIP_MEMORY_SCOPE_AGENT);
    if (a == nwg - 1){
      __hip_atomic_store(cnt, 0, __ATOMIC_RELAXED, __HIP_MEMORY_SCOPE_AGENT);
      __hip_atomic_store(gen, g + 1, __ATOMIC_RELEASE, __HIP_MEMORY_SCOPE_AGENT);
    } else {
      while (__hip_atomic_load(gen, __ATOMIC_ACQUIRE, __HIP_MEMORY_SCOPE_AGENT) == g)
        __builtin_amdgcn_s_sleep(1);
      __threadfence(); // acquire
    }
  }
  __syncthreads();
}

// ---------------- persistent encoder GRU recurrence (H=1024) ----------------
// 64 WGs x 128 threads. WG wg owns hidden cols [wg*16, wg*16+16) for all 3 gates.
__global__ __launch_bounds__(128) void enc_rec(
    const u16* __restrict__ gi,   // [GG, 3072], row = b*TT + t (bih included)
    const u16* __restrict__ whh,  // [3072, 1024]
    const u16* __restrict__ bhh,  // [3072]
    u16* __restrict__ seq,        // out [GG, 1024]
    int* cnt, int* gen)
{
  const int wg = blockIdx.x;          // 0..63
  const int wave = threadIdx.x >> 6;  // 0..1
  const int lane = threadIdx.x & 63;
  const int q = lane >> 4, lr = lane & 15;
  const int j = wg*16 + lr;
  const int bbase = wave*16;
  const float bh_r = b2f(bhh[j]);
  const float bh_z = b2f(bhh[H8 + j]);
  const float bh_n = b2f(bhh[2*H8 + j]);
  const u16* bp0 = whh + (size_t)(0*H8 + j)*H8 + q*8;
  const u16* bp1 = whh + (size_t)(1*H8 + j)*H8 + q*8;
  const u16* bp2 = whh + (size_t)(2*H8 + j)*H8 + q*8;
  float hreg[4] = {0.f,0.f,0.f,0.f};
  for (int t = 0; t < TT; t++){
    float gr_i[4], gz_i[4], gn_i[4];
    #pragma unroll
    for (int r = 0; r < 4; r++){
      size_t row = ((size_t)(bbase + q*4 + r)*TT + t)*(size_t)H3;
      gr_i[r] = b2f(gi[row + j]);
      gz_i[r] = b2f(gi[row + H8 + j]);
      gn_i[r] = b2f(gi[row + 2*H8 + j]);
    }
    f32x4 acc0 = {}, acc1 = {}, acc2 = {};
    if (t > 0){
      const u16* ap = seq + ((size_t)(bbase + lr)*TT + (t-1))*(size_t)H8 + q*8;
      for (int kb = 0; kb < H8; kb += 32){
        bf16x8 a   = *(const bf16x8*)(ap + kb);
        bf16x8 w0v = *(const bf16x8*)(bp0 + kb);
        bf16x8 w1v = *(const bf16x8*)(bp1 + kb);
        bf16x8 w2v = *(const bf16x8*)(bp2 + kb);
        acc0 = __builtin_amdgcn_mfma_f32_16x16x32_bf16(a, w0v, acc0, 0,0,0);
        acc1 = __builtin_amdgcn_mfma_f32_16x16x32_bf16(a, w1v, acc1, 0,0,0);
        acc2 = __builtin_amdgcn_mfma_f32_16x16x32_bf16(a, w2v, acc2, 0,0,0);
      }
    }
    #pragma unroll
    for (int r = 0; r < 4; r++){
      int b = bbase + q*4 + r;
      float rr = sigm(gr_i[r] + acc0[r] + bh_r);
      float zz = sigm(gz_i[r] + acc1[r] + bh_z);
      float nn = tanh_f(gn_i[r] + rr*(acc2[r] + bh_n));
      float hnew = (1.f - zz)*nn + zz*hreg[r];
      hreg[r] = hnew;
      seq[((size_t)b*TT + t)*(size_t)H8 + j] = f2b(hnew);
    }
    grid_barrier(cnt, gen, 64);
  }
}

// ---------------- decoder GRU recurrence (H=128) ----------------
// 2 WGs x 256 threads; WG handles 16 batches. whh in registers; LDS = h history.
__global__ __launch_bounds__(256) void dec_rec(
    const u16* __restrict__ gi,   // [GG, 384] (bih included)
    const u16* __restrict__ whh,  // [384, 128]
    const u16* __restrict__ bhh,  // [384]
    u16* __restrict__ seq)        // out [GG, 128]
{
  __shared__ u16 hlds[16*136];
  const int bb = blockIdx.x*16;
  const int tid = threadIdx.x;
  const int w = tid >> 6, lane = tid & 63, q = lane >> 4, lr = lane & 15;
  bf16x8 wreg[3][2][4];
  #pragma unroll
  for (int g2 = 0; g2 < 3; g2++)
    #pragma unroll
    for (int nt = 0; nt < 2; nt++){
      int j = g2*128 + w*32 + nt*16 + lr;
      #pragma unroll
      for (int kb = 0; kb < 4; kb++)
        wreg[g2][nt][kb] = *(const bf16x8*)(whh + (size_t)j*128 + kb*32 + q*8);
    }
  float bh[3][2];
  #pragma unroll
  for (int g2 = 0; g2 < 3; g2++)
    #pragma unroll
    for (int nt = 0; nt < 2; nt++)
      bh[g2][nt] = b2f(bhh[g2*128 + w*32 + nt*16 + lr]);
  float hreg[2][4] = {};
  __syncthreads();
  for (int t = 0; t < TT; t++){
    float gir[2][4], giz[2][4], gin[2][4];
    #pragma unroll
    for (int r = 0; r < 4; r++){
      size_t row = ((size_t)(bb + q*4 + r)*TT + t)*(size_t)384;
      #pragma unroll
      for (int nt = 0; nt < 2; nt++){
        int j = w*32 + nt*16 + lr;
        gir[nt][r] = b2f(gi[row + j]);
        giz[nt][r] = b2f(gi[row + 128 + j]);
        gin[nt][r] = b2f(gi[row + 256 + j]);
      }
    }
    f32x4 acc[3][2] = {};
    if (t > 0){
      #pragma unroll
      for (int kb = 0; kb < 4; kb++){
        bf16x8 a = *(const bf16x8*)(hlds + lr*136 + kb*32 + q*8);
        #pragma unroll
        for (int g2 = 0; g2 < 3; g2++)
          #pragma unroll
          for (int nt = 0; nt < 2; nt++)
            acc[g2][nt] = __builtin_amdgcn_mfma_f32_16x16x32_bf16(a, wreg[g2][nt][kb], acc[g2][nt], 0,0,0);
      }
    }
    __syncthreads();   // MFMA reads of hlds done before rewrites
    #pragma unroll
    for (int nt = 0; nt < 2; nt++)
      #pragma unroll
      for (int r = 0; r < 4; r++){
        int j = w*32 + nt*16 + lr;
        int b = bb + q*4 + r;
        float rr = sigm(gir[nt][r] + acc[0][nt][r] + bh[0][nt]);
        float zz = sigm(giz[nt][r] + acc[1][nt][r] + bh[1][nt]);
        float nn = tanh_f(gin[nt][r] + rr*(acc[2][nt][r] + bh[2][nt]));
        float hnew = (1.f - zz)*nn + zz*hreg[nt][r];
        hreg[nt][r] = hnew;
        hlds[(b - bb)*136 + j] = f2b(hnew);
        seq[((size_t)b*TT + t)*(size_t)128 + j] = f2b(hnew);
      }
    __syncthreads();
  }
}

extern "C" void kernel_launch(void* const* d_in, const int* in_sizes, int n_in,
                              void* d_out, int out_size, void* d_ws, size_t ws_size,
                              hipStream_t stream)
{
  const void* x    = d_in[0];
  const int* ei    = (const int*)d_in[1];

  const size_t NEED = (size_t)164 << 20;
  if (ws_size < NEED) return;   // signature: zero output (absmax 0.613) => ws too small
  char* wsb = (char*)d_ws;
  const size_t KB = 1024, MB = 1024*1024;

  int* syncv = (int*)wsb;                       // 0..256B: barrier counters
  int* flag  = (int*)(wsb + 256);               // dtype flag (1 = fp32 inputs)
  // canonical bf16 copies of all float tensors:
  u16* gw1_c  = (u16*)(wsb + 1*MB + 0);
  u16* gb1_c  = (u16*)(wsb + 1*MB + 64);
  u16* gw2_c  = (u16*)(wsb + 1*MB + 128);
  u16* gb2_c  = (u16*)(wsb + 1*MB + 192);
  u16* gcw_c  = (u16*)(wsb + 1*MB + 256);
  u16* gcb_c  = (u16*)(wsb + 1*MB + 320);
  u16* efb_c  = (u16*)(wsb + 1*MB + 4*KB);      // 1024
  u16* ebih_c = (u16*)(wsb + 1*MB + 8*KB);      // 6144
  u16* ebhh_c = (u16*)(wsb + 1*MB + 24*KB);     // 6144
  u16* dfb_c  = (u16*)(wsb + 1*MB + 40*KB);     // 1024
  u16* dbih_c = (u16*)(wsb + 1*MB + 45*KB);     // 768
  u16* dbhh_c = (u16*)(wsb + 1*MB + 47*KB);     // 768
  u16* dlb_c  = (u16*)(wsb + 1*MB + 49*KB);     // 128
  u16* wT3    = (u16*)(wsb + 1*MB + 64*KB);     // 32KB  dec_lin_w^T [128,128]
  u16* dlw_c  = (u16*)(wsb + 1*MB + 128*KB);    // 32KB
  u16* efw_c  = (u16*)(wsb + 1*MB + 192*KB);    // 256KB [128,1024]
  u16* wT1    = (u16*)(wsb + 1*MB + 448*KB);    // 256KB enc_fl_w^T [1024,128]
  u16* dfw_c  = (u16*)(wsb + 2*MB);             // 2MB [1024,1024]
  u16* wT2    = (u16*)(wsb + 4*MB);             // 2MB dec_fl_w^T
  u16* dwih0_c= (u16*)(wsb + 6*MB);             // 768KB [384,1024]
  u16* dwih1_c= (u16*)(wsb + 7*MB);             // 96KB [384,128]
  u16* dwhh_c = (u16*)(wsb + 7*MB + 128*KB);    // 192KB [2,384,128]
  u16* ewih_c = (u16*)(wsb + 8*MB);             // 12MB [2,3072,1024]
  u16* ewhh_c = (u16*)(wsb + 20*MB);            // 12MB
  u16* res    = (u16*)(wsb + 32*MB);            // 4MB  [GG,128]
  u16* bufA   = (u16*)(wsb + 36*MB);            // 32MB [GG,1024]
  u16* bufC   = (u16*)(wsb + 68*MB);            // 96MB [GG,3072]
  u16* x_c    = bufC;                           // 4MB alias (dead before gi written)
  u16* giD    = (u16*)(wsb + 100*MB);           // 12MB alias in bufC tail

  hipMemsetAsync(syncv, 0, 256, stream);
  detect_dtype<<<1, 256, 0, stream>>>(x, flag);

  auto cvt = [&](int idx, u16* dst, int n){
    cvt_bf16<<<(n + 255)/256, 256, 0, stream>>>(d_in[idx], dst, n, flag);
  };
  cvt(0,  x_c,     GG*NNODE*2);
  cvt(2,  gw1_c, 8);  cvt(3, gb1_c, 4);  cvt(4, gw2_c, 8);
  cvt(5,  gb2_c, 2);  cvt(6, gcw_c, 4);  cvt(7, gcb_c, 2);
  cvt(8,  efw_c,   128*1024);   cvt(9,  efb_c, 1024);
  cvt(10, ewih_c,  2*3072*1024);
  cvt(11, ewhh_c,  2*3072*1024);
  cvt(12, ebih_c,  2*3072);     cvt(13, ebhh_c, 2*3072);
  cvt(14, dfw_c,   1024*1024);  cvt(15, dfb_c, 1024);
  cvt(16, dwih0_c, 384*1024);   cvt(17, dwih1_c, 384*128);
  cvt(18, dwhh_c,  2*384*128);
  cvt(19, dbih_c,  2*384);      cvt(20, dbhh_c, 2*384);
  cvt(21, dlw_c,   128*128);    cvt(22, dlb_c, 128);

  // weight transposes ([K,N] -> [N,K] for the NT GEMM)
  transpose_bf16<<<dim3(1024/32, 128/32),  dim3(32,8), 0, stream>>>(efw_c, wT1, 128, 1024);
  transpose_bf16<<<dim3(1024/32, 1024/32), dim3(32,8), 0, stream>>>(dfw_c, wT2, 1024, 1024);
  transpose_bf16<<<dim3(128/32, 128/32),   dim3(32,8), 0, stream>>>(dlw_c, wT3, 128, 128);

  // GCN -> res [GG,128]
  gcn_kernel<<<GG, 64, 0, stream>>>(x_c, ei, gw1_c, gb1_c, gw2_c, gb2_c, gcw_c, gcb_c, res);

  // encoder fl: x0 = relu(res @ efw + efb) -> bufA
  gemm_nt<<<dim3(1024/128, GG/128), 256, 0, stream>>>(res, wT1, efb_c, bufA, GG, 1024, 128, 1, nullptr);
  // enc layer 0: gi0 -> bufC ; recurrence -> bufA (seq1)
  gemm_nt<<<dim3(3072/128, GG/128), 256, 0, stream>>>(bufA, ewih_c, ebih_c, bufC, GG, 3072, 1024, 0, nullptr);
  enc_rec<<<64, 128, 0, stream>>>(bufC, ewhh_c, ebhh_c, bufA, syncv + 0, syncv + 1);
  // enc layer 1: gi1 -> bufC ; recurrence -> bufA (seq2)
  gemm_nt<<<dim3(3072/128, GG/128), 256, 0, stream>>>(bufA, ewih_c + 3072*1024, ebih_c + 3072, bufC, GG, 3072, 1024, 0, nullptr);
  enc_rec<<<64, 128, 0, stream>>>(bufC, ewhh_c + 3072*1024, ebhh_c + 3072, bufA, syncv + 8, syncv + 9);

  // decoder fl: d0 = relu(seq2 @ dfw + dfb) -> bufC[0:32MB]
  u16* d0 = bufC;
  gemm_nt<<<dim3(1024/128, GG/128), 256, 0, stream>>>(bufA, wT2, dfb_c, d0, GG, 1024, 1024, 1, nullptr);
  // dec layer 0: gi -> giD ; recurrence -> res (seq3)
  gemm_nt<<<dim3(384/128, GG/128), 256, 0, stream>>>(d0, dwih0_c, dbih_c, giD, GG, 384, 1024, 0, nullptr);
  dec_rec<<<2, 256, 0, stream>>>(giD, dwhh_c, dbhh_c, res);
  // dec layer 1: gi -> giD ; recurrence -> bufA (seq4)
  gemm_nt<<<dim3(384/128, GG/128), 256, 0, stream>>>(res, dwih1_c, dbih_c + 384, giD, GG, 384, 128, 0, nullptr);
  dec_rec<<<2, 256, 0, stream>>>(giD, dwhh_c + 384*128, dbhh_c + 384, bufA);

  // final linear -> d_out (bf16 or f32 per detected dtype)
  gemm_nt<<<dim3(128/128, GG/128), 256, 0, stream>>>(bufA, wT3, dlb_c, d_out, GG, 128, 128, 0, flag);
}

// Round 4
// 12467.251 us; speedup vs baseline: 1.4612x; 1.4612x over previous
//
#include <hip/hip_runtime.h>

typedef unsigned short u16;
typedef unsigned long long u64;
typedef __attribute__((ext_vector_type(8))) short bf16x8;
typedef __attribute__((ext_vector_type(4))) float f32x4;

#define BSZ 32
#define TT 512
#define GG (BSZ*TT)      // 16384
#define NNODE 64
#define EE 126
#define H8 1024
#define H3 3072
#define NWAVE 128        // enc_rec waves (= WGs)

__device__ __forceinline__ float b2f(u16 u){
  union { unsigned i; float f; } v; v.i = ((unsigned)u) << 16; return v.f;
}
__device__ __forceinline__ u16 f2b(float f){
  unsigned i = __float_as_uint(f);
  unsigned r = (i + 0x7FFFu + ((i >> 16) & 1u)) >> 16;   // RNE
  return (u16)r;
}
__device__ __forceinline__ float sigm(float x){ return 1.f/(1.f+__expf(-x)); }
__device__ __forceinline__ float tanh_f(float x){
  float xc = fminf(fmaxf(x, -15.f), 15.f);
  float e = __expf(2.f*xc);
  return (e-1.f)/(e+1.f);
}
// sequence-row permutation: logical row m = b*TT+t  ->  physical row t*BSZ+b
__device__ __forceinline__ int prow(int m, int perm){
  return perm ? ((m & (TT-1))*BSZ + (m >> 9)) : m;
}

// ---------------- dtype detection: *flag = 1 if inputs are fp32 ----------------
__global__ __launch_bounds__(256) void detect_dtype(const void* xraw, int* flag){
  __shared__ int cnt;
  if (threadIdx.x == 0) cnt = 0;
  __syncthreads();
  const u16* p = (const u16*)xraw;
  u16 u = p[2*threadIdx.x];
  int e = (u >> 7) & 0xFF;
  int weird = (e < 100 || e > 134) ? 1 : 0;
  atomicAdd(&cnt, weird);
  __syncthreads();
  if (threadIdx.x == 0) *flag = (cnt > 128) ? 1 : 0;
}

// canonicalize a float tensor to bf16 (pass-through copy if already bf16)
__global__ __launch_bounds__(256) void cvt_bf16(const void* __restrict__ in,
                                                u16* __restrict__ out, int n,
                                                const int* __restrict__ flag){
  int i = blockIdx.x*256 + threadIdx.x;
  if (i >= n) return;
  if (*flag) out[i] = f2b(((const float*)in)[i]);
  else       out[i] = ((const u16*)in)[i];
}

// ---------------- GCN: one block per graph, one thread per node ----------------
__global__ __launch_bounds__(64) void gcn_kernel(
    const u16* __restrict__ x, const int* __restrict__ ei,
    const u16* __restrict__ w1, const u16* __restrict__ b1,
    const u16* __restrict__ w2, const u16* __restrict__ b2,
    const u16* __restrict__ cw, const u16* __restrict__ cb,
    u16* __restrict__ res)
{
  __shared__ int se[EE], de[EE];
  __shared__ float dinv[NNODE];
  __shared__ float nrm[EE];
  __shared__ float hs[NNODE][4];
  const int n = threadIdx.x;
  const int g = blockIdx.x;
  for (int e = n; e < EE; e += 64){ se[e] = ei[e]; de[e] = ei[EE + e]; }
  __syncthreads();
  int cnt = 0;
  for (int e = 0; e < EE; e++) cnt += (de[e] == n) ? 1 : 0;
  float di = rsqrtf(1.0f + (float)cnt);
  dinv[n] = di;
  float x0 = b2f(x[((size_t)g*NNODE + n)*2 + 0]);
  float x1 = b2f(x[((size_t)g*NNODE + n)*2 + 1]);
  float hw[4];
  #pragma unroll
  for (int c = 0; c < 4; c++) hw[c] = x0*b2f(w1[c]) + x1*b2f(w1[4+c]);
  #pragma unroll
  for (int c = 0; c < 4; c++) hs[n][c] = hw[c];
  __syncthreads();
  for (int e = n; e < EE; e += 64) nrm[e] = dinv[se[e]] * dinv[de[e]];
  __syncthreads();
  float selfc = di*di;
  float agg[4];
  #pragma unroll
  for (int c = 0; c < 4; c++) agg[c] = hw[c]*selfc;
  for (int e = 0; e < EE; e++){
    if (de[e] == n){
      float w = nrm[e]; int s = se[e];
      #pragma unroll
      for (int c = 0; c < 4; c++) agg[c] += hs[s][c]*w;
    }
  }
  float h1[4];
  #pragma unroll
  for (int c = 0; c < 4; c++) h1[c] = tanh_f(agg[c] + b2f(b1[c]));
  __syncthreads();
  float hw2[2];
  #pragma unroll
  for (int c = 0; c < 2; c++){
    float s = 0.f;
    #pragma unroll
    for (int k = 0; k < 4; k++) s += h1[k]*b2f(w2[k*2+c]);
    hw2[c] = s;
    hs[n][c] = s;
  }
  __syncthreads();
  float agg2[2] = { hw2[0]*selfc, hw2[1]*selfc };
  for (int e = 0; e < EE; e++){
    if (de[e] == n){
      float w = nrm[e]; int s = se[e];
      agg2[0] += hs[s][0]*w;
      agg2[1] += hs[s][1]*w;
    }
  }
  float h2a = tanh_f(agg2[0] + b2f(b2[0]));
  float h2b = tanh_f(agg2[1] + b2f(b2[1]));
  #pragma unroll
  for (int c = 0; c < 2; c++){
    float o = h2a*b2f(cw[c]) + h2b*b2f(cw[2+c]) + b2f(cb[c]);
    res[(size_t)g*128 + n*2 + c] = f2b(o);
  }
}

// ---------------- bf16 transpose: out[c][r] = in[r][c] ----------------
__global__ __launch_bounds__(256) void transpose_bf16(
    const u16* __restrict__ in, u16* __restrict__ out, int R, int C)
{
  __shared__ u16 tile[32][33];
  int c0 = blockIdx.x*32, r0 = blockIdx.y*32;
  for (int i = threadIdx.y; i < 32; i += 8)
    tile[i][threadIdx.x] = in[(size_t)(r0+i)*C + c0 + threadIdx.x];
  __syncthreads();
  for (int i = threadIdx.y; i < 32; i += 8)
    out[(size_t)(c0+i)*R + r0 + threadIdx.x] = tile[threadIdx.x][i];
}

// ---------------- C[M,N] = act(A[M,K] * Bm[N,K]^T + bias) ----------------
// permA/permC: remap sequence rows b*TT+t <-> physical t*BSZ+b.
__global__ __launch_bounds__(256) void gemm_nt(
    const u16* __restrict__ A, const u16* __restrict__ Bm,
    const u16* __restrict__ bias, void* __restrict__ C,
    int M, int N, int K, int relu, int permA, int permC,
    const int* __restrict__ outflag)
{
  const int wave = threadIdx.x >> 6;
  const int lane = threadIdx.x & 63;
  const int wm = wave >> 1, wn = wave & 1;
  const int q = lane >> 4, lr = lane & 15;
  const int mBase = blockIdx.y*128 + wm*64;
  const int nBase = blockIdx.x*128 + wn*64;
  f32x4 acc[4][4] = {};
  const u16* ap[4]; const u16* bp[4];
  #pragma unroll
  for (int i = 0; i < 4; i++){
    ap[i] = A + (size_t)prow(mBase + i*16 + lr, permA)*K + q*8;
    bp[i] = Bm + (size_t)(nBase + i*16 + lr)*K + q*8;
  }
  for (int kb = 0; kb < K; kb += 32){
    bf16x8 av[4], bv[4];
    #pragma unroll
    for (int i = 0; i < 4; i++){
      av[i] = *(const bf16x8*)ap[i]; bv[i] = *(const bf16x8*)bp[i];
      ap[i] += 32; bp[i] += 32;
    }
    #pragma unroll
    for (int mi = 0; mi < 4; mi++)
      #pragma unroll
      for (int ni = 0; ni < 4; ni++)
        acc[mi][ni] = __builtin_amdgcn_mfma_f32_16x16x32_bf16(av[mi], bv[ni], acc[mi][ni], 0, 0, 0);
  }
  const int of32 = outflag ? *outflag : 0;
  #pragma unroll
  for (int ni = 0; ni < 4; ni++){
    int col = nBase + ni*16 + lr;
    float bb = bias ? b2f(bias[col]) : 0.f;
    #pragma unroll
    for (int mi = 0; mi < 4; mi++){
      #pragma unroll
      for (int r = 0; r < 4; r++){
        int row = prow(mBase + mi*16 + q*4 + r, permC);
        float v = acc[mi][ni][r] + bb;
        if (relu) v = fmaxf(v, 0.f);
        size_t idx = (size_t)row*N + col;
        if (of32) ((float*)C)[idx] = v;
        else      ((u16*)C)[idx]   = f2b(v);
      }
    }
  }
}

// ---------------- persistent encoder GRU recurrence (H=1024) ----------------
// 128 WGs x 64 threads (1 wave each, no intra-WG sync). Wave wg: hidden cols
// [ (wg>>1)*16, +16 ) x 3 gates, batches [(wg&1)*16, +16). Per-step sync via
// monotone per-step counters (8 cacheline-split sub-counters, target 128).
// All h traffic uses relaxed AGENT-scope atomics (L2-bypass -> L3-coherent);
// no threadfence / cache maintenance anywhere. gi prefetched 1 step ahead.
__global__ __launch_bounds__(64) void enc_rec(
    const u16* __restrict__ gi,   // [TT*BSZ, 3072]  row = t*32+b (bih included)
    const u16* __restrict__ whh,  // [3072, 1024]
    const u16* __restrict__ bhh,  // [3072]
    u16* __restrict__ seq,        // out [TT*BSZ, 1024] row = t*32+b
    int* __restrict__ cnt)        // [8*TT] sub-counter blocks
{
  const int wg = blockIdx.x;
  const int lane = threadIdx.x & 63;
  const int q = lane >> 4, lr = lane & 15;
  const int j = (wg >> 1)*16 + lr;
  const int bbase = (wg & 1)*16;
  const int sub = wg & 7;
  const float bh_r = b2f(bhh[j]);
  const float bh_z = b2f(bhh[H8 + j]);
  const float bh_n = b2f(bhh[2*H8 + j]);
  const u16* wp0 = whh + (size_t)(0*H8 + j)*H8 + q*8;
  const u16* wp1 = whh + (size_t)(1*H8 + j)*H8 + q*8;
  const u16* wp2 = whh + (size_t)(2*H8 + j)*H8 + q*8;
  float hreg[4] = {0.f,0.f,0.f,0.f};
  u16 gpre[12];
  // prefetch gi for t=0
  #pragma unroll
  for (int r = 0; r < 4; r++){
    size_t row = (size_t)(bbase + q*4 + r)*H3;
    gpre[r]   = gi[row + j];
    gpre[4+r] = gi[row + H8 + j];
    gpre[8+r] = gi[row + 2*H8 + j];
  }
  for (int t = 0; t < TT; t++){
    if (t > 0){
      // wait for all 128 waves to have published h[t-1]
      for (;;){
        int s = 0;
        #pragma unroll
        for (int i = 0; i < 8; i++)
          s += __hip_atomic_load(&cnt[i*TT + (t-1)], __ATOMIC_RELAXED, __HIP_MEMORY_SCOPE_AGENT);
        if (s == NWAVE) break;
        __builtin_amdgcn_s_sleep(1);
      }
      asm volatile("" ::: "memory");
    }
    // consume prefetched gi
    float gr_[4], gz_[4], gn_[4];
    #pragma unroll
    for (int r = 0; r < 4; r++){
      gr_[r] = b2f(gpre[r]); gz_[r] = b2f(gpre[4+r]); gn_[r] = b2f(gpre[8+r]);
    }
    f32x4 acc0 = {}, acc1 = {}, acc2 = {};
    if (t > 0){
      const u16* ap = seq + (size_t)((t-1)*BSZ + bbase + lr)*H8 + q*8;
      #pragma unroll 8
      for (int kb = 0; kb < 32; kb++){
        const u64* p = (const u64*)(ap + kb*32);
        u64 lo = __hip_atomic_load(p,     __ATOMIC_RELAXED, __HIP_MEMORY_SCOPE_AGENT);
        u64 hi = __hip_atomic_load(p + 1, __ATOMIC_RELAXED, __HIP_MEMORY_SCOPE_AGENT);
        union { u64 v[2]; bf16x8 b; } a; a.v[0] = lo; a.v[1] = hi;
        bf16x8 w0 = *(const bf16x8*)(wp0 + kb*32);
        bf16x8 w1 = *(const bf16x8*)(wp1 + kb*32);
        bf16x8 w2 = *(const bf16x8*)(wp2 + kb*32);
        acc0 = __builtin_amdgcn_mfma_f32_16x16x32_bf16(a.b, w0, acc0, 0,0,0);
        acc1 = __builtin_amdgcn_mfma_f32_16x16x32_bf16(a.b, w1, acc1, 0,0,0);
        acc2 = __builtin_amdgcn_mfma_f32_16x16x32_bf16(a.b, w2, acc2, 0,0,0);
      }
    }
    #pragma unroll
    for (int r = 0; r < 4; r++){
      float rr = sigm(gr_[r] + acc0[r] + bh_r);
      float zz = sigm(gz_[r] + acc1[r] + bh_z);
      float nn = tanh_f(gn_[r] + rr*(acc2[r] + bh_n));
      float hnew = (1.f - zz)*nn + zz*hreg[r];
      hreg[r] = hnew;
      __hip_atomic_store(&seq[(size_t)(t*BSZ + bbase + q*4 + r)*H8 + j], f2b(hnew),
                         __ATOMIC_RELAXED, __HIP_MEMORY_SCOPE_AGENT);
    }
    asm volatile("s_waitcnt vmcnt(0)" ::: "memory");   // h stores are L3-visible
    if (lane == 0)
      __hip_atomic_fetch_add(&cnt[sub*TT + t], 1, __ATOMIC_RELAXED, __HIP_MEMORY_SCOPE_AGENT);
    if (t + 1 < TT){   // prefetch next gi while (others) spin
      #pragma unroll
      for (int r = 0; r < 4; r++){
        size_t row = (size_t)((t+1)*BSZ + bbase + q*4 + r)*H3;
        gpre[r]   = gi[row + j];
        gpre[4+r] = gi[row + H8 + j];
        gpre[8+r] = gi[row + 2*H8 + j];
      }
    }
  }
}

// ---------------- decoder GRU recurrence (H=128) ----------------
// 2 WGs x 256 threads; WG handles 16 batches. whh in registers; LDS = h history;
// gi in [t][b] layout, prefetched one step ahead.
__global__ __launch_bounds__(256) void dec_rec(
    const u16* __restrict__ gi,   // [TT*BSZ, 384] row = t*32+b (bih included)
    const u16* __restrict__ whh,  // [384, 128]
    const u16* __restrict__ bhh,  // [384]
    u16* __restrict__ seq)        // out [TT*BSZ, 128] row = t*32+b
{
  __shared__ u16 hlds[16*136];
  const int bb = blockIdx.x*16;
  const int tid = threadIdx.x;
  const int w = tid >> 6, lane = tid & 63, q = lane >> 4, lr = lane & 15;
  bf16x8 wreg[3][2][4];
  #pragma unroll
  for (int g2 = 0; g2 < 3; g2++)
    #pragma unroll
    for (int nt = 0; nt < 2; nt++){
      int jj = g2*128 + w*32 + nt*16 + lr;
      #pragma unroll
      for (int kb = 0; kb < 4; kb++)
        wreg[g2][nt][kb] = *(const bf16x8*)(whh + (size_t)jj*128 + kb*32 + q*8);
    }
  float bh[3][2];
  #pragma unroll
  for (int g2 = 0; g2 < 3; g2++)
    #pragma unroll
    for (int nt = 0; nt < 2; nt++)
      bh[g2][nt] = b2f(bhh[g2*128 + w*32 + nt*16 + lr]);
  float hreg[2][4] = {};
  u16 gpre[3][2][4];
  #pragma unroll
  for (int r = 0; r < 4; r++){
    size_t row = (size_t)(bb + q*4 + r)*384;
    #pragma unroll
    for (int nt = 0; nt < 2; nt++){
      int jj = w*32 + nt*16 + lr;
      #pragma unroll
      for (int g2 = 0; g2 < 3; g2++)
        gpre[g2][nt][r] = gi[row + g2*128 + jj];
    }
  }
  __syncthreads();
  for (int t = 0; t < TT; t++){
    float gif[3][2][4];
    #pragma unroll
    for (int g2 = 0; g2 < 3; g2++)
      #pragma unroll
      for (int nt = 0; nt < 2; nt++)
        #pragma unroll
        for (int r = 0; r < 4; r++)
          gif[g2][nt][r] = b2f(gpre[g2][nt][r]);
    f32x4 acc[3][2] = {};
    if (t > 0){
      #pragma unroll
      for (int kb = 0; kb < 4; kb++){
        bf16x8 a = *(const bf16x8*)(hlds + lr*136 + kb*32 + q*8);
        #pragma unroll
        for (int g2 = 0; g2 < 3; g2++)
          #pragma unroll
          for (int nt = 0; nt < 2; nt++)
            acc[g2][nt] = __builtin_amdgcn_mfma_f32_16x16x32_bf16(a, wreg[g2][nt][kb], acc[g2][nt], 0,0,0);
      }
    }
    __syncthreads();   // MFMA reads of hlds done before rewrites
    #pragma unroll
    for (int nt = 0; nt < 2; nt++)
      #pragma unroll
      for (int r = 0; r < 4; r++){
        int jj = w*32 + nt*16 + lr;
        int b = bb + q*4 + r;
        float rr = sigm(gif[0][nt][r] + acc[0][nt][r] + bh[0][nt]);
        float zz = sigm(gif[1][nt][r] + acc[1][nt][r] + bh[1][nt]);
        float nn = tanh_f(gif[2][nt][r] + rr*(acc[2][nt][r] + bh[2][nt]));
        float hnew = (1.f - zz)*nn + zz*hreg[nt][r];
        hreg[nt][r] = hnew;
        u16 hb = f2b(hnew);
        hlds[(q*4 + r)*136 + jj] = hb;
        seq[(size_t)(t*BSZ + b)*128 + jj] = hb;
      }
    if (t + 1 < TT){
      #pragma unroll
      for (int r = 0; r < 4; r++){
        size_t row = (size_t)((t+1)*BSZ + bb + q*4 + r)*384;
        #pragma unroll
        for (int nt = 0; nt < 2; nt++){
          int jj = w*32 + nt*16 + lr;
          #pragma unroll
          for (int g2 = 0; g2 < 3; g2++)
            gpre[g2][nt][r] = gi[row + g2*128 + jj];
        }
      }
    }
    __syncthreads();   // hlds writes done before next step's reads
  }
}

extern "C" void kernel_launch(void* const* d_in, const int* in_sizes, int n_in,
                              void* d_out, int out_size, void* d_ws, size_t ws_size,
                              hipStream_t stream)
{
  const void* x    = d_in[0];
  const int* ei    = (const int*)d_in[1];

  const size_t NEED = (size_t)164 << 20;
  if (ws_size < NEED) return;   // signature: zero output => ws too small
  char* wsb = (char*)d_ws;
  const size_t KB = 1024, MB = 1024*1024;

  int* syncv = (int*)wsb;                       // 32 KB: 2 layers x 8x512 counters
  int* flag  = (int*)(wsb + 40*KB);             // dtype flag (1 = fp32 inputs)
  u16* gw1_c  = (u16*)(wsb + 1*MB + 0);
  u16* gb1_c  = (u16*)(wsb + 1*MB + 64);
  u16* gw2_c  = (u16*)(wsb + 1*MB + 128);
  u16* gb2_c  = (u16*)(wsb + 1*MB + 192);
  u16* gcw_c  = (u16*)(wsb + 1*MB + 256);
  u16* gcb_c  = (u16*)(wsb + 1*MB + 320);
  u16* efb_c  = (u16*)(wsb + 1*MB + 4*KB);
  u16* ebih_c = (u16*)(wsb + 1*MB + 8*KB);
  u16* ebhh_c = (u16*)(wsb + 1*MB + 24*KB);
  u16* dfb_c  = (u16*)(wsb + 1*MB + 40*KB);
  u16* dbih_c = (u16*)(wsb + 1*MB + 45*KB);
  u16* dbhh_c = (u16*)(wsb + 1*MB + 47*KB);
  u16* dlb_c  = (u16*)(wsb + 1*MB + 49*KB);
  u16* wT3    = (u16*)(wsb + 1*MB + 64*KB);
  u16* dlw_c  = (u16*)(wsb + 1*MB + 128*KB);
  u16* efw_c  = (u16*)(wsb + 1*MB + 192*KB);
  u16* wT1    = (u16*)(wsb + 1*MB + 448*KB);
  u16* dfw_c  = (u16*)(wsb + 2*MB);
  u16* wT2    = (u16*)(wsb + 4*MB);
  u16* dwih0_c= (u16*)(wsb + 6*MB);
  u16* dwih1_c= (u16*)(wsb + 7*MB);
  u16* dwhh_c = (u16*)(wsb + 7*MB + 128*KB);
  u16* ewih_c = (u16*)(wsb + 8*MB);
  u16* ewhh_c = (u16*)(wsb + 20*MB);
  u16* res    = (u16*)(wsb + 32*MB);            // 4MB  [GG,128]
  u16* bufA   = (u16*)(wsb + 36*MB);            // 32MB [GG,1024]
  u16* bufC   = (u16*)(wsb + 68*MB);            // 96MB [GG,3072]
  u16* x_c    = bufC;                           // 4MB alias (dead before gi written)
  u16* giD    = (u16*)(wsb + 100*MB);           // 12MB alias in bufC tail

  hipMemsetAsync(syncv, 0, 32*KB, stream);
  detect_dtype<<<1, 256, 0, stream>>>(x, flag);

  auto cvt = [&](int idx, u16* dst, int n){
    cvt_bf16<<<(n + 255)/256, 256, 0, stream>>>(d_in[idx], dst, n, flag);
  };
  cvt(0,  x_c,     GG*NNODE*2);
  cvt(2,  gw1_c, 8);  cvt(3, gb1_c, 4);  cvt(4, gw2_c, 8);
  cvt(5,  gb2_c, 2);  cvt(6, gcw_c, 4);  cvt(7, gcb_c, 2);
  cvt(8,  efw_c,   128*1024);   cvt(9,  efb_c, 1024);
  cvt(10, ewih_c,  2*3072*1024);
  cvt(11, ewhh_c,  2*3072*1024);
  cvt(12, ebih_c,  2*3072);     cvt(13, ebhh_c, 2*3072);
  cvt(14, dfw_c,   1024*1024);  cvt(15, dfb_c, 1024);
  cvt(16, dwih0_c, 384*1024);   cvt(17, dwih1_c, 384*128);
  cvt(18, dwhh_c,  2*384*128);
  cvt(19, dbih_c,  2*384);      cvt(20, dbhh_c, 2*384);
  cvt(21, dlw_c,   128*128);    cvt(22, dlb_c, 128);

  transpose_bf16<<<dim3(1024/32, 128/32),  dim3(32,8), 0, stream>>>(efw_c, wT1, 128, 1024);
  transpose_bf16<<<dim3(1024/32, 1024/32), dim3(32,8), 0, stream>>>(dfw_c, wT2, 1024, 1024);
  transpose_bf16<<<dim3(128/32, 128/32),   dim3(32,8), 0, stream>>>(dlw_c, wT3, 128, 128);

  // GCN -> res [GG,128] (row = b*TT+t)
  gcn_kernel<<<GG, 64, 0, stream>>>(x_c, ei, gw1_c, gb1_c, gw2_c, gb2_c, gcw_c, gcb_c, res);

  // encoder fl: x0 = relu(res @ efw + efb) -> bufA [t][b]
  gemm_nt<<<dim3(1024/128, GG/128), 256, 0, stream>>>(res, wT1, efb_c, bufA, GG, 1024, 128, 1, 0, 1, nullptr);
  // enc layer 0: gi0 -> bufC [t][b]; recurrence -> bufA (seq1, [t][b])
  gemm_nt<<<dim3(3072/128, GG/128), 256, 0, stream>>>(bufA, ewih_c, ebih_c, bufC, GG, 3072, 1024, 0, 1, 1, nullptr);
  enc_rec<<<NWAVE, 64, 0, stream>>>(bufC, ewhh_c, ebhh_c, bufA, syncv);
  // enc layer 1: gi1 -> bufC [t][b]; recurrence -> bufA (seq2)
  gemm_nt<<<dim3(3072/128, GG/128), 256, 0, stream>>>(bufA, ewih_c + 3072*1024, ebih_c + 3072, bufC, GG, 3072, 1024, 0, 1, 1, nullptr);
  enc_rec<<<NWAVE, 64, 0, stream>>>(bufC, ewhh_c + 3072*1024, ebhh_c + 3072, bufA, syncv + 8*TT);

  // decoder fl: d0 = relu(seq2 @ dfw + dfb) -> bufC[0:32MB] [t][b]
  u16* d0 = bufC;
  gemm_nt<<<dim3(1024/128, GG/128), 256, 0, stream>>>(bufA, wT2, dfb_c, d0, GG, 1024, 1024, 1, 1, 1, nullptr);
  // dec layer 0: gi -> giD [t][b]; recurrence -> res (seq3, [t][b])
  gemm_nt<<<dim3(384/128, GG/128), 256, 0, stream>>>(d0, dwih0_c, dbih_c, giD, GG, 384, 1024, 0, 1, 1, nullptr);
  dec_rec<<<2, 256, 0, stream>>>(giD, dwhh_c, dbhh_c, res);
  // dec layer 1: gi -> giD [t][b]; recurrence -> bufA (seq4, [t][b])
  gemm_nt<<<dim3(384/128, GG/128), 256, 0, stream>>>(res, dwih1_c, dbih_c + 384, giD, GG, 384, 128, 0, 1, 1, nullptr);
  dec_rec<<<2, 256, 0, stream>>>(giD, dwhh_c + 384*128, dbhh_c + 384, bufA);

  // final linear: A = seq4 [t][b] -> d_out rows b*TT+t (bf16 or f32 per dtype)
  gemm_nt<<<dim3(128/128, GG/128), 256, 0, stream>>>(bufA, wT3, dlb_c, d_out, GG, 128, 128, 0, 1, 0, flag);
}